// Round 1
// baseline (50.512 us; speedup 1.0000x reference)
//
#include <hip/hip_runtime.h>

#define CHUNK 8
#define NCHUNK 64
#define TDIM 512
#define HW 9216          // 96*96
#define NT 256           // threads per block
#define F4_PER_CH (HW/4) // 2304 float4 per channel
#define ITERS (F4_PER_CH/NT) // 9

typedef float floatx4 __attribute__((ext_vector_type(4)));

__host__ __device__ constexpr int TRI(int c, int j) {       // c<=j incl diag, 36 entries
    return (c*(15-c))/2 + j;
}
__host__ __device__ constexpr int PairIdx(int c, int j) {   // c<j strict, 28 entries
    return 7*c - (c*(c-1))/2 + (j - c - 1);
}

__global__ __launch_bounds__(NT, 2)
void lcsap_kernel(const float* __restrict__ x,
                  const float* __restrict__ Wq, const float* __restrict__ bq,
                  const float* __restrict__ Wk, const float* __restrict__ bk,
                  const float* __restrict__ Wv, const float* __restrict__ bv,
                  float* __restrict__ out)
{
    const int bid = blockIdx.x;
    const int b   = bid >> 6;   // batch
    const int n   = bid & 63;   // chunk
    const int tid = threadIdx.x;
    const int lane = tid & 63;
    const int wid  = tid >> 6;

    const float* xb = x + ((size_t)(b*TDIM + n*CHUNK)) * HW;
    float* ob = out + ((size_t)(b*NCHUNK + n)) * HW;

    __shared__ float red[4][44];
    __shared__ float Gf[64];   // full symmetric Gram
    __shared__ float sf[8];    // row sums
    __shared__ float Mld[64];  // M = attn * Wv
    __shared__ float tld[8];   // t = attn * bv

    // ---------------- pass 1: Gram matrix + row sums ----------------
    float g[36];
    float sr[8];
    #pragma unroll
    for (int i = 0; i < 36; ++i) g[i] = 0.f;
    #pragma unroll
    for (int c = 0; c < 8; ++c) sr[c] = 0.f;

    for (int it = 0; it < ITERS; ++it) {
        const int f = tid + it*NT;
        floatx4 q[8];
        #pragma unroll
        for (int c = 0; c < 8; ++c)
            q[c] = reinterpret_cast<const floatx4*>(xb + (size_t)c*HW)[f];
        #pragma unroll
        for (int u = 0; u < 4; ++u) {
            float xv[8];
            #pragma unroll
            for (int c = 0; c < 8; ++c) xv[c] = q[c][u];
            #pragma unroll
            for (int c = 0; c < 8; ++c) sr[c] += xv[c];
            #pragma unroll
            for (int c = 0; c < 8; ++c) {
                #pragma unroll
                for (int j = c; j < 8; ++j)
                    g[TRI(c,j)] += xv[c]*xv[j];
            }
        }
    }

    // wave-level butterfly reduce (all 64 lanes end with full-wave sum)
    #pragma unroll
    for (int i = 0; i < 36; ++i) {
        g[i] += __shfl_xor(g[i], 1);  g[i] += __shfl_xor(g[i], 2);
        g[i] += __shfl_xor(g[i], 4);  g[i] += __shfl_xor(g[i], 8);
        g[i] += __shfl_xor(g[i], 16); g[i] += __shfl_xor(g[i], 32);
    }
    #pragma unroll
    for (int c = 0; c < 8; ++c) {
        sr[c] += __shfl_xor(sr[c], 1);  sr[c] += __shfl_xor(sr[c], 2);
        sr[c] += __shfl_xor(sr[c], 4);  sr[c] += __shfl_xor(sr[c], 8);
        sr[c] += __shfl_xor(sr[c], 16); sr[c] += __shfl_xor(sr[c], 32);
    }
    if (lane == 0) {
        #pragma unroll
        for (int i = 0; i < 36; ++i) red[wid][i] = g[i];
        #pragma unroll
        for (int c = 0; c < 8; ++c) red[wid][36+c] = sr[c];
    }
    __syncthreads();
    if (tid < 44) {
        float v = red[0][tid] + red[1][tid] + red[2][tid] + red[3][tid];
        if (tid < 36) {
            int c = 0, base = 0;
            for (; c < 8; ++c) { int w = 8 - c; if (tid < base + w) break; base += w; }
            int j = c + (tid - base);
            Gf[c*8+j] = v;
            Gf[j*8+c] = v;
        } else {
            sf[tid-36] = v;
        }
    }
    __syncthreads();

    // ---------------- tiny 8x8 attention on wave 0 ----------------
    if (tid < 64) {
        const int qi = tid >> 3;
        const int ki = tid & 7;
        float wq[8], wk[8];
        #pragma unroll
        for (int c = 0; c < 8; ++c) {
            wq[c] = Wq[n*64 + qi*8 + c];
            wk[c] = Wk[n*64 + ki*8 + c];
        }
        float sc = 0.f, qs = 0.f, ks_ = 0.f;
        #pragma unroll
        for (int c = 0; c < 8; ++c) {
            float tmp = 0.f;
            #pragma unroll
            for (int d = 0; d < 8; ++d) tmp += Gf[c*8+d]*wk[d];
            sc += wq[c]*tmp;
            qs += wq[c]*sf[c];
            ks_ += wk[c]*sf[c];
        }
        const float bqv = bq[n*8+qi];
        const float bkv = bk[n*8+ki];
        sc += qs*bkv + bqv*ks_ + (float)HW * bqv * bkv;
        sc *= (1.0f/96.0f);   // 1/sqrt(9216)

        // softmax over ki within each 8-lane group
        float m = sc;
        m = fmaxf(m, __shfl_xor(m, 1, 8));
        m = fmaxf(m, __shfl_xor(m, 2, 8));
        m = fmaxf(m, __shfl_xor(m, 4, 8));
        float e = expf(sc - m);
        float se = e;
        se += __shfl_xor(se, 1, 8);
        se += __shfl_xor(se, 2, 8);
        se += __shfl_xor(se, 4, 8);
        const float attn = e / se;

        // M[qi][ki] = sum_k attn[qi][k] * Wv[n][k][ki]
        float mv = 0.f;
        #pragma unroll
        for (int k = 0; k < 8; ++k) {
            float ak = __shfl(attn, k, 8);
            mv += ak * Wv[n*64 + k*8 + ki];
        }
        Mld[qi*8 + ki] = mv;

        // t[qi] = sum_k attn[qi][k] * bv[n][k]
        float tv = attn * bv[n*8 + ki];
        tv += __shfl_xor(tv, 1, 8);
        tv += __shfl_xor(tv, 2, 8);
        tv += __shfl_xor(tv, 4, 8);
        if (ki == 0) tld[qi] = tv;
    }
    __syncthreads();

    // ---------------- pass 2: pooled[p] = x_p^T M x_p + t^T x_p ----------------
    float diag[8], tt[8], su[28];
    #pragma unroll
    for (int c = 0; c < 8; ++c) { diag[c] = Mld[c*9]; tt[c] = tld[c]; }
    #pragma unroll
    for (int c = 0; c < 8; ++c) {
        #pragma unroll
        for (int j = c+1; j < 8; ++j)
            su[PairIdx(c,j)] = Mld[c*8+j] + Mld[j*8+c];
    }

    for (int it = 0; it < ITERS; ++it) {
        const int f = tid + it*NT;
        floatx4 q[8];
        #pragma unroll
        for (int c = 0; c < 8; ++c)
            q[c] = reinterpret_cast<const floatx4*>(xb + (size_t)c*HW)[f];
        floatx4 o;
        #pragma unroll
        for (int u = 0; u < 4; ++u) {
            float xv[8];
            #pragma unroll
            for (int c = 0; c < 8; ++c) xv[c] = q[c][u];
            float acc = 0.f;
            #pragma unroll
            for (int c = 0; c < 8; ++c) acc += tt[c]*xv[c];
            #pragma unroll
            for (int c = 0; c < 8; ++c) acc += diag[c]*xv[c]*xv[c];
            #pragma unroll
            for (int c = 0; c < 8; ++c) {
                #pragma unroll
                for (int j = c+1; j < 8; ++j)
                    acc += su[PairIdx(c,j)]*xv[c]*xv[j];
            }
            o[u] = acc;
        }
        reinterpret_cast<floatx4*>(ob)[f] = o;
    }
}

extern "C" void kernel_launch(void* const* d_in, const int* in_sizes, int n_in,
                              void* d_out, int out_size, void* d_ws, size_t ws_size,
                              hipStream_t stream) {
    const float* x  = (const float*)d_in[0];
    const float* Wq = (const float*)d_in[1];
    const float* bq = (const float*)d_in[2];
    const float* Wk = (const float*)d_in[3];
    const float* bk = (const float*)d_in[4];
    const float* Wv = (const float*)d_in[5];
    const float* bv = (const float*)d_in[6];
    float* out = (float*)d_out;

    lcsap_kernel<<<dim3(512), dim3(NT), 0, stream>>>(x, Wq, bq, Wk, bk, Wv, bv, out);
}

// Round 2
// 50.246 us; speedup vs baseline: 1.0053x; 1.0053x over previous
//
#include <hip/hip_runtime.h>

#define CHUNK 8
#define NCHUNK 64
#define TDIM 512
#define HW 9216          // 96*96
#define NT 256           // threads per block
#define F4_PER_CH (HW/4) // 2304 float4 per channel
#define ITERS (F4_PER_CH/NT) // 9

typedef float floatx4 __attribute__((ext_vector_type(4)));

__host__ __device__ constexpr int TRI(int c, int j) {       // c<=j incl diag, 36 entries
    return (c*(15-c))/2 + j;
}
__host__ __device__ constexpr int PairIdx(int c, int j) {   // c<j strict, 28 entries
    return 7*c - (c*(c-1))/2 + (j - c - 1);
}

// Register-resident fused kernel: x slice held in VGPRs across
// reduce + attention, so x is read from HBM exactly once.
// 72 float4 data regs/thread -> ~360 VGPR peak -> 1 wave/SIMD; latency
// hidden by MLP (72 outstanding 16B loads per wave).
__global__ __launch_bounds__(NT, 1)
void lcsap_kernel(const float* __restrict__ x,
                  const float* __restrict__ Wq, const float* __restrict__ bq,
                  const float* __restrict__ Wk, const float* __restrict__ bk,
                  const float* __restrict__ Wv, const float* __restrict__ bv,
                  float* __restrict__ out)
{
    const int bid = blockIdx.x;
    const int b   = bid >> 6;   // batch
    const int n   = bid & 63;   // chunk
    const int tid = threadIdx.x;
    const int lane = tid & 63;
    const int wid  = tid >> 6;

    const float* xb = x + ((size_t)(b*TDIM + n*CHUNK)) * HW;
    float* ob = out + ((size_t)(b*NCHUNK + n)) * HW;

    __shared__ float red[4][44];
    __shared__ float Gf[64];   // full symmetric Gram
    __shared__ float sf[8];    // row sums
    __shared__ float Mld[64];  // M = attn * Wv
    __shared__ float tld[8];   // t = attn * bv

    // ---------------- load entire slice into registers ----------------
    floatx4 q[8][ITERS];
    #pragma unroll
    for (int it = 0; it < ITERS; ++it) {
        const int f = tid + it*NT;
        #pragma unroll
        for (int c = 0; c < 8; ++c)
            q[c][it] = reinterpret_cast<const floatx4*>(xb + (size_t)c*HW)[f];
    }

    // ---------------- pass 1: Gram matrix + row sums ----------------
    float g[36];
    float sr[8];
    #pragma unroll
    for (int i = 0; i < 36; ++i) g[i] = 0.f;
    #pragma unroll
    for (int c = 0; c < 8; ++c) sr[c] = 0.f;

    #pragma unroll
    for (int it = 0; it < ITERS; ++it) {
        #pragma unroll
        for (int u = 0; u < 4; ++u) {
            #pragma unroll
            for (int c = 0; c < 8; ++c) sr[c] += q[c][it][u];
            #pragma unroll
            for (int c = 0; c < 8; ++c) {
                #pragma unroll
                for (int j = c; j < 8; ++j)
                    g[TRI(c,j)] += q[c][it][u]*q[j][it][u];
            }
        }
    }

    // wave-level butterfly reduce (all 64 lanes end with full-wave sum)
    #pragma unroll
    for (int i = 0; i < 36; ++i) {
        g[i] += __shfl_xor(g[i], 1);  g[i] += __shfl_xor(g[i], 2);
        g[i] += __shfl_xor(g[i], 4);  g[i] += __shfl_xor(g[i], 8);
        g[i] += __shfl_xor(g[i], 16); g[i] += __shfl_xor(g[i], 32);
    }
    #pragma unroll
    for (int c = 0; c < 8; ++c) {
        sr[c] += __shfl_xor(sr[c], 1);  sr[c] += __shfl_xor(sr[c], 2);
        sr[c] += __shfl_xor(sr[c], 4);  sr[c] += __shfl_xor(sr[c], 8);
        sr[c] += __shfl_xor(sr[c], 16); sr[c] += __shfl_xor(sr[c], 32);
    }
    if (lane == 0) {
        #pragma unroll
        for (int i = 0; i < 36; ++i) red[wid][i] = g[i];
        #pragma unroll
        for (int c = 0; c < 8; ++c) red[wid][36+c] = sr[c];
    }
    __syncthreads();
    if (tid < 44) {
        float v = red[0][tid] + red[1][tid] + red[2][tid] + red[3][tid];
        if (tid < 36) {
            int c = 0, base = 0;
            for (; c < 8; ++c) { int w = 8 - c; if (tid < base + w) break; base += w; }
            int j = c + (tid - base);
            Gf[c*8+j] = v;
            Gf[j*8+c] = v;
        } else {
            sf[tid-36] = v;
        }
    }
    __syncthreads();

    // ---------------- tiny 8x8 attention on wave 0 ----------------
    if (tid < 64) {
        const int qi = tid >> 3;
        const int ki = tid & 7;
        float wq[8], wk[8];
        #pragma unroll
        for (int c = 0; c < 8; ++c) {
            wq[c] = Wq[n*64 + qi*8 + c];
            wk[c] = Wk[n*64 + ki*8 + c];
        }
        float sc = 0.f, qs = 0.f, ks_ = 0.f;
        #pragma unroll
        for (int c = 0; c < 8; ++c) {
            float tmp = 0.f;
            #pragma unroll
            for (int d = 0; d < 8; ++d) tmp += Gf[c*8+d]*wk[d];
            sc += wq[c]*tmp;
            qs += wq[c]*sf[c];
            ks_ += wk[c]*sf[c];
        }
        const float bqv = bq[n*8+qi];
        const float bkv = bk[n*8+ki];
        sc += qs*bkv + bqv*ks_ + (float)HW * bqv * bkv;
        sc *= (1.0f/96.0f);   // 1/sqrt(9216)

        // softmax over ki within each 8-lane group
        float m = sc;
        m = fmaxf(m, __shfl_xor(m, 1, 8));
        m = fmaxf(m, __shfl_xor(m, 2, 8));
        m = fmaxf(m, __shfl_xor(m, 4, 8));
        float e = expf(sc - m);
        float se = e;
        se += __shfl_xor(se, 1, 8);
        se += __shfl_xor(se, 2, 8);
        se += __shfl_xor(se, 4, 8);
        const float attn = e / se;

        // M[qi][ki] = sum_k attn[qi][k] * Wv[n][k][ki]
        float mv = 0.f;
        #pragma unroll
        for (int k = 0; k < 8; ++k) {
            float ak = __shfl(attn, k, 8);
            mv += ak * Wv[n*64 + k*8 + ki];
        }
        Mld[qi*8 + ki] = mv;

        // t[qi] = sum_k attn[qi][k] * bv[n][k]
        float tv = attn * bv[n*8 + ki];
        tv += __shfl_xor(tv, 1, 8);
        tv += __shfl_xor(tv, 2, 8);
        tv += __shfl_xor(tv, 4, 8);
        if (ki == 0) tld[qi] = tv;
    }
    __syncthreads();

    // ---------------- pass 2 (from registers): pooled = x^T M x + t^T x ----
    float diag[8], tt[8], su[28];
    #pragma unroll
    for (int c = 0; c < 8; ++c) { diag[c] = Mld[c*9]; tt[c] = tld[c]; }
    #pragma unroll
    for (int c = 0; c < 8; ++c) {
        #pragma unroll
        for (int j = c+1; j < 8; ++j)
            su[PairIdx(c,j)] = Mld[c*8+j] + Mld[j*8+c];
    }

    #pragma unroll
    for (int it = 0; it < ITERS; ++it) {
        const int f = tid + it*NT;
        floatx4 o;
        #pragma unroll
        for (int u = 0; u < 4; ++u) {
            float acc = 0.f;
            #pragma unroll
            for (int c = 0; c < 8; ++c) acc += tt[c]*q[c][it][u];
            #pragma unroll
            for (int c = 0; c < 8; ++c) acc += diag[c]*q[c][it][u]*q[c][it][u];
            #pragma unroll
            for (int c = 0; c < 8; ++c) {
                #pragma unroll
                for (int j = c+1; j < 8; ++j)
                    acc += su[PairIdx(c,j)]*q[c][it][u]*q[j][it][u];
            }
            o[u] = acc;
        }
        reinterpret_cast<floatx4*>(ob)[f] = o;
    }
}

extern "C" void kernel_launch(void* const* d_in, const int* in_sizes, int n_in,
                              void* d_out, int out_size, void* d_ws, size_t ws_size,
                              hipStream_t stream) {
    const float* x  = (const float*)d_in[0];
    const float* Wq = (const float*)d_in[1];
    const float* bq = (const float*)d_in[2];
    const float* Wk = (const float*)d_in[3];
    const float* bk = (const float*)d_in[4];
    const float* Wv = (const float*)d_in[5];
    const float* bv = (const float*)d_in[6];
    float* out = (float*)d_out;

    lcsap_kernel<<<dim3(512), dim3(NT), 0, stream>>>(x, Wq, bq, Wk, bk, Wv, bv, out);
}